// Round 8
// baseline (279.258 us; speedup 1.0000x reference)
//
#include <hip/hip_runtime.h>
#include <math.h>

#define H 28
#define N 784
#define B 32
#define T 25
#define NPAD 1024
#define CH 16
#define MEDGE 1536
#define NCHUNK 24   // MEDGE / 64

// ---- numpy linspace replication (float64) ----
__device__ __forceinline__ double coord_r(int i) {
    if (i == H - 1) return 0.0;
    return 224.0 + (double)i * ((0.0 - 224.0) / 27.0);
}
__device__ __forceinline__ double coord_c(int j) {
    if (j == H - 1) return 224.0;
    return (double)j * (224.0 / 27.0);
}

// ============================================================
// K1: per-row sort by u32 key (int_d2<<10 | j).
// ============================================================
__global__ void sort_d2_kernel(float* __restrict__ d2s_t,
                               unsigned short* __restrict__ sidx_t) {
    __shared__ unsigned key[NPAD];
    const int i = blockIdx.x, tid = threadIdx.x;
    const int ri = i / H, ci = i % H;
    for (int j = tid; j < NPAD; j += 256) {
        if (j < N) {
            int dr = ri - j / H, dc = ci - j % H;
            key[j] = ((unsigned)(dr * dr + dc * dc) << 10) | (unsigned)j;
        } else {
            key[j] = 0xFFFFFFFFu;
        }
    }
    __syncthreads();
    for (int k = 2; k <= NPAD; k <<= 1) {
        for (int j = k >> 1; j > 0; j >>= 1) {
            for (int a = tid; a < NPAD; a += 256) {
                int b = a ^ j;
                if (b > a) {
                    unsigned ka = key[a], kb = key[b];
                    if ((ka > kb) == ((a & k) == 0)) { key[a] = kb; key[b] = ka; }
                }
            }
            __syncthreads();
        }
    }
    const double rri = coord_r(ri), cci = coord_c(ci);
    for (int j = tid; j < N; j += 256) {
        int jj = (int)(key[j] & 1023u);
        double dr = rri - coord_r(jj / H);
        double dc = cci - coord_c(jj % H);
        d2s_t[j * N + i]  = (float)(dr * dr + dc * dc);
        sidx_t[j * N + i] = (unsigned short)jj;
    }
}

// ============================================================
// K2: DTM. 1024 threads, one sorted-walk per thread, early exit.
// ============================================================
__global__ __launch_bounds__(1024) void dtm_kernel(
        const float* __restrict__ x,
        const float* __restrict__ d2s_t,
        const unsigned short* __restrict__ sidx_t,
        float* __restrict__ fv_g) {
    __shared__ float lw[N];
    __shared__ float red[1024];
    const int prob = blockIdx.x;
    const int b  = prob & 31;
    const int mi = prob >> 5;
    const float m0 = mi ? 0.2f : 0.05f;
    const int tid = threadIdx.x;
    float s = 0.f;
    if (tid < N) { float v = x[b * N + tid]; lw[tid] = v; s = v; }
    red[tid] = s;
    __syncthreads();
    for (int off = 512; off > 0; off >>= 1) {
        if (tid < off) red[tid] += red[tid + off];
        __syncthreads();
    }
    const float m0W = m0 * red[0];
    if (tid < N) {
        const int i = tid;
        float cum = 0.f, acc = 0.f;
        for (int k0 = 0; k0 < N; k0 += CH) {
            float d2c[CH]; int idc[CH];
            #pragma unroll
            for (int c = 0; c < CH; ++c) {
                d2c[c] = d2s_t[(k0 + c) * N + i];
                idc[c] = sidx_t[(k0 + c) * N + i];
            }
            float swc[CH];
            #pragma unroll
            for (int c = 0; c < CH; ++c) swc[c] = lw[idc[c]];
            #pragma unroll
            for (int c = 0; c < CH; ++c) {
                float rem = m0W - cum;
                float contrib = fminf(fmaxf(rem, 0.f), swc[c]);
                acc += contrib * d2c[c];
                cum += swc[c];
            }
            if (cum >= m0W) break;   // all later contribs are exactly 0
        }
        fv_g[prob * N + i] = sqrtf(fmaxf(acc / m0W, 1e-12f));
    }
}

// ============================================================
// K3 (fused): argsort + edge list (1 scan) + wave-0 branchless
// Kruskal + landscapes. One 512-thread block per (m0, b).
// ============================================================
__device__ __forceinline__ int pf_find(volatile float2* pf, int x, unsigned& fbits) {
    float2 e;
    e.x = pf[x].x; e.y = pf[x].y;
    int p = __float_as_int(e.y);
    while (p != x) {
        float2 ep;
        ep.x = pf[p].x; ep.y = pf[p].y;
        int gp = __float_as_int(ep.y);
        if (gp != p) { pf[x].x = ep.x; pf[x].y = ep.y; }   // path halving
        x = p; e = ep; p = gp;
    }
    fbits = __float_as_uint(e.x);
    return x;
}

__global__ __launch_bounds__(512) void topo_kernel(
        const float* __restrict__ fv_g,
        float* __restrict__ feat) {
    __shared__ float skey[NPAD];
    __shared__ short sidx_s[NPAD];
    __shared__ short rank_[N];
    __shared__ int tcnt[NPAD];
    __shared__ int tcnt2[NPAD];
    __shared__ float fv[N];
    __shared__ float2 pf_s[N];
    __shared__ short pd[N];
    __shared__ unsigned ev[MEDGE];
    volatile float2* pf = pf_s;

    const int prob = blockIdx.x, tid = threadIdx.x;

    // ---- load f, init sort arrays ----
    for (int j = tid; j < NPAD; j += 512) {
        float v = (j < N) ? fv_g[prob * N + j] : 3.0e38f;
        skey[j] = v;
        sidx_s[j] = (short)j;
        if (j < N) fv[j] = v;
    }
    __syncthreads();
    // ---- stable bitonic argsort ascending by (f, idx) ----
    for (int k = 2; k <= NPAD; k <<= 1) {
        for (int j = k >> 1; j > 0; j >>= 1) {
            for (int a = tid; a < NPAD; a += 512) {
                int b2 = a ^ j;
                if (b2 > a) {
                    float ka = skey[a], kb = skey[b2];
                    short ia = sidx_s[a], ib = sidx_s[b2];
                    bool gt = (ka > kb) || (ka == kb && ia > ib);
                    if (gt == ((a & k) == 0)) {
                        skey[a] = kb; skey[b2] = ka;
                        sidx_s[a] = ib; sidx_s[b2] = ia;
                    }
                }
            }
            __syncthreads();
        }
    }
    // ---- rank, pf, pd init ----
    for (int j = tid; j < N; j += 512) {
        rank_[sidx_s[j]] = (short)j;
        pf_s[j] = make_float2(fv[j], __int_as_float(j));
        pd[j] = (short)j;
    }
    __syncthreads();
    // ---- deg per rank ----
    #pragma unroll
    for (int h = 0; h < 2; ++h) {
        int r = tid + h * 512;
        int deg = 0;
        if (r < N) {
            int v = sidx_s[r];
            int row = v / H, col = v % H;
            deg += (row > 0     && (int)rank_[v - H] < r);
            deg += (row < H - 1 && (int)rank_[v + H] < r);
            deg += (col > 0     && (int)rank_[v - 1] < r);
            deg += (col < H - 1 && (int)rank_[v + 1] < r);
        }
        tcnt[r] = deg;
    }
    __syncthreads();
    // ---- inclusive Hillis-Steele scan over 1024 (ping-pong) ----
    int src_is_a = 1;
    for (int off = 1; off < NPAD; off <<= 1) {
        int* src = src_is_a ? tcnt : tcnt2;
        int* dst = src_is_a ? tcnt2 : tcnt;
        #pragma unroll
        for (int h = 0; h < 2; ++h) {
            int i = tid + h * 512;
            int v = src[i];
            if (i >= off) v += src[i - off];
            dst[i] = v;
        }
        __syncthreads();
        src_is_a ^= 1;
    }
    int* scan = src_is_a ? tcnt : tcnt2;   // 10 steps -> result back in tcnt
    // ---- scatter ordered edges ----
    #pragma unroll
    for (int h = 0; h < 2; ++h) {
        int r = tid + h * 512;
        if (r < N) {
            int v = sidx_s[r];
            int row = v / H, col = v % H;
            int nbs[4] = { v - H, v + H, v - 1, v + 1 };
            bool val[4] = { row > 0, row < H - 1, col > 0, col < H - 1 };
            int deg = 0;
            #pragma unroll
            for (int k4 = 0; k4 < 4; ++k4)
                deg += (val[k4] && (int)rank_[nbs[k4]] < r);
            int pos = scan[r] - deg;
            #pragma unroll
            for (int k4 = 0; k4 < 4; ++k4) {
                if (val[k4] && (int)rank_[nbs[k4]] < r) {
                    ev[pos] = (unsigned)v | ((unsigned)nbs[k4] << 16);
                    pos++;
                }
            }
        }
    }
    const int m = scan[NPAD - 1];
    for (int j = m + tid; j < MEDGE; j += 512) ev[j] = 0u;  // inert pad
    __syncthreads();

    // ---- wave-0 Kruskal: parallel finds + branchless unrolled resolve ----
    if (tid < 64) {
        const int lane = tid;
        unsigned cur = ev[lane];
        for (int c = 0; c < NCHUNK; ++c) {
            unsigned nxt = (c + 1 < NCHUNK) ? ev[(c + 1) * 64 + lane] : 0u;
            const int vv = (int)(cur & 0xFFFFu);
            const int nb = (int)(cur >> 16);
            unsigned fa, fb;
            int ra = pf_find(pf, vv, fa);
            int rb = pf_find(pf, nb, fb);
            int myL = -1, myW = 0; unsigned myWF = 0;
            #pragma unroll
            for (int j = 0; j < 64; ++j) {
                int s_a = __builtin_amdgcn_readlane(ra, j);
                int s_b = __builtin_amdgcn_readlane(rb, j);
                unsigned s_fa = (unsigned)__builtin_amdgcn_readlane((int)fa, j);
                unsigned s_fb = (unsigned)__builtin_amdgcn_readlane((int)fb, j);
                bool valid = (s_a != s_b);
                bool nw = (s_fb < s_fa) || (s_fb == s_fa && s_b < s_a);
                int s_w = nw ? s_b : s_a;
                int s_l = nw ? s_a : s_b;
                unsigned s_wf = nw ? s_fb : s_fa;
                bool ha = valid && (ra == s_l);
                ra = ha ? s_w : ra;
                fa = ha ? s_wf : fa;
                bool hb = valid && (rb == s_l);
                rb = hb ? s_w : rb;
                fb = hb ? s_wf : fb;
                bool me = valid && (lane == j);
                myL  = me ? s_l  : myL;
                myW  = me ? s_w  : myW;
                myWF = me ? s_wf : myWF;
            }
            // one parallel write round; losers distinct -> race-free
            if (myL >= 0) {
                pd[myL] = (short)vv;
                pf[myL].x = __uint_as_float(myWF);
                pf[myL].y = __int_as_float(myW);
            }
            __builtin_amdgcn_sched_barrier(0);   // writes before next finds
            cur = nxt;
        }
        if (lane == 0) {
            unsigned dummy;
            int vmax = (int)sidx_s[N - 1];
            int g = pf_find(pf, vmax, dummy);
            pd[g] = (short)vmax;
        }
    }
    __syncthreads();

    // ---- landscapes: top-2 of tent functions per t (8 waves) ----
    const int wave = tid >> 6, lane = tid & 63;
    for (int t = wave; t < T; t += 8) {
        float tval = (t == T - 1) ? 80.0f : (1.0f + (float)t * (79.0f / 24.0f));
        float m1 = 0.f, m2 = 0.f;
        for (int i = lane; i < N; i += 64) {
            float bi = fv[i];
            float di = fv[(int)pd[i]];
            float tv = fminf(tval - bi, di - tval);
            tv = fmaxf(tv, 0.f);
            float lo = fminf(tv, m1);
            m1 = fmaxf(tv, m1);
            m2 = fmaxf(m2, lo);
        }
        #pragma unroll
        for (int off = 32; off > 0; off >>= 1) {
            float o1 = __shfl_down(m1, off, 64);
            float o2 = __shfl_down(m2, off, 64);
            float hi = fmaxf(m1, o1);
            float lo = fminf(m1, o1);
            m2 = fmaxf(fmaxf(m2, o2), lo);
            m1 = hi;
        }
        if (lane == 0) {
            feat[prob * 50 + t]     = m1;
            feat[prob * 50 + T + t] = m2;
        }
    }
}

// ============================================================
// K4: head.
// ============================================================
__global__ void head_kernel(const float* __restrict__ feat,
                            const float* __restrict__ wg1, const float* __restrict__ bg1,
                            const float* __restrict__ wg2, const float* __restrict__ bg2,
                            const float* __restrict__ fcw, const float* __restrict__ fcb,
                            float* __restrict__ out) {
    __shared__ float xc[B * 100];
    const int tid = threadIdx.x;
    for (int e = tid; e < B * 100; e += 256) {
        int b = e / 100, j = e % 100;
        const float* fp; const float* wrow; float bias;
        if (j < 50) { fp = feat + b * 50;       wrow = wg1 + j * 50;        bias = bg1[j]; }
        else        { fp = feat + (B + b) * 50; wrow = wg2 + (j - 50) * 50; bias = bg2[j - 50]; }
        float acc = bias;
        for (int q = 0; q < 50; ++q) acc += fp[q] * wrow[q];
        xc[e] = acc;
    }
    __syncthreads();
    for (int j = tid; j < 100; j += 256) {
        float s = 0.f;
        for (int b = 0; b < B; ++b) s += fabsf(xc[b * 100 + j]);
        out[320 + j] = s;
    }
    for (int e = tid; e < 320; e += 256) {
        int b = e / 10, o = e % 10;
        float acc = fcb[o];
        for (int j = 0; j < 100; ++j)
            acc += fmaxf(xc[b * 100 + j], 0.f) * fcw[o * 100 + j];
        out[e] = acc;
    }
}

extern "C" void kernel_launch(void* const* d_in, const int* in_sizes, int n_in,
                              void* d_out, int out_size, void* d_ws, size_t ws_size,
                              hipStream_t stream) {
    (void)in_sizes; (void)n_in; (void)out_size; (void)ws_size;
    const float* x   = (const float*)d_in[0];
    const float* wg1 = (const float*)d_in[1];
    const float* bg1 = (const float*)d_in[2];
    const float* wg2 = (const float*)d_in[3];
    const float* bg2 = (const float*)d_in[4];
    const float* fcw = (const float*)d_in[5];
    const float* fcb = (const float*)d_in[6];
    float* out = (float*)d_out;

    char* ws = (char*)d_ws;
    float*          d2s   = (float*)ws;                                  // N*N f32
    unsigned short* sidxt = (unsigned short*)(ws + (size_t)N * N * 4);   // N*N u16
    float*          fv_g  = (float*)(ws + (size_t)N * N * 6);            // 64*784 f32
    float*          feat  = (float*)(ws + (size_t)N * N * 6 + 64 * N * 4); // 64*50 f32

    sort_d2_kernel<<<dim3(N), dim3(256), 0, stream>>>(d2s, sidxt);
    dtm_kernel<<<dim3(64), dim3(1024), 0, stream>>>(x, d2s, sidxt, fv_g);
    topo_kernel<<<dim3(64), dim3(512), 0, stream>>>(fv_g, feat);
    head_kernel<<<dim3(1), dim3(256), 0, stream>>>(feat, wg1, bg1, wg2, bg2, fcw, fcb, out);
}

// Round 9
// 122.734 us; speedup vs baseline: 2.2753x; 2.2753x over previous
//
#include <hip/hip_runtime.h>
#include <math.h>

#define H 28
#define N 784
#define B 32
#define T 25
#define NPAD 1024
#define CH 16
#define MEDGE 1536

// ---- numpy linspace replication (float64) ----
__device__ __forceinline__ double coord_r(int i) {
    if (i == H - 1) return 0.0;
    return 224.0 + (double)i * ((0.0 - 224.0) / 27.0);
}
__device__ __forceinline__ double coord_c(int j) {
    if (j == H - 1) return 224.0;
    return (double)j * (224.0 / 27.0);
}

// ============================================================
// K1: per-row sort by u32 key (int_d2<<10 | j).
// ============================================================
__global__ void sort_d2_kernel(float* __restrict__ d2s_t,
                               unsigned short* __restrict__ sidx_t) {
    __shared__ unsigned key[NPAD];
    const int i = blockIdx.x, tid = threadIdx.x;
    const int ri = i / H, ci = i % H;
    for (int j = tid; j < NPAD; j += 256) {
        if (j < N) {
            int dr = ri - j / H, dc = ci - j % H;
            key[j] = ((unsigned)(dr * dr + dc * dc) << 10) | (unsigned)j;
        } else {
            key[j] = 0xFFFFFFFFu;
        }
    }
    __syncthreads();
    for (int k = 2; k <= NPAD; k <<= 1) {
        for (int j = k >> 1; j > 0; j >>= 1) {
            for (int a = tid; a < NPAD; a += 256) {
                int b = a ^ j;
                if (b > a) {
                    unsigned ka = key[a], kb = key[b];
                    if ((ka > kb) == ((a & k) == 0)) { key[a] = kb; key[b] = ka; }
                }
            }
            __syncthreads();
        }
    }
    const double rri = coord_r(ri), cci = coord_c(ci);
    for (int j = tid; j < N; j += 256) {
        int jj = (int)(key[j] & 1023u);
        double dr = rri - coord_r(jj / H);
        double dc = cci - coord_c(jj % H);
        d2s_t[j * N + i]  = (float)(dr * dr + dc * dc);
        sidx_t[j * N + i] = (unsigned short)jj;
    }
}

// ============================================================
// K2: DTM. 1024 threads, one sorted-walk per thread, early exit.
// ============================================================
__global__ __launch_bounds__(1024) void dtm_kernel(
        const float* __restrict__ x,
        const float* __restrict__ d2s_t,
        const unsigned short* __restrict__ sidx_t,
        float* __restrict__ fv_g) {
    __shared__ float lw[N];
    __shared__ float red[1024];
    const int prob = blockIdx.x;
    const int b  = prob & 31;
    const int mi = prob >> 5;
    const float m0 = mi ? 0.2f : 0.05f;
    const int tid = threadIdx.x;
    float s = 0.f;
    if (tid < N) { float v = x[b * N + tid]; lw[tid] = v; s = v; }
    red[tid] = s;
    __syncthreads();
    for (int off = 512; off > 0; off >>= 1) {
        if (tid < off) red[tid] += red[tid + off];
        __syncthreads();
    }
    const float m0W = m0 * red[0];
    if (tid < N) {
        const int i = tid;
        float cum = 0.f, acc = 0.f;
        for (int k0 = 0; k0 < N; k0 += CH) {
            float d2c[CH]; int idc[CH];
            #pragma unroll
            for (int c = 0; c < CH; ++c) {
                d2c[c] = d2s_t[(k0 + c) * N + i];
                idc[c] = sidx_t[(k0 + c) * N + i];
            }
            float swc[CH];
            #pragma unroll
            for (int c = 0; c < CH; ++c) swc[c] = lw[idc[c]];
            #pragma unroll
            for (int c = 0; c < CH; ++c) {
                float rem = m0W - cum;
                float contrib = fminf(fmaxf(rem, 0.f), swc[c]);
                acc += contrib * d2c[c];
                cum += swc[c];
            }
            if (cum >= m0W) break;   // all later contribs are exactly 0
        }
        fv_g[prob * N + i] = sqrtf(fmaxf(acc / m0W, 1e-12f));
    }
}

// ============================================================
// K3 (fused): argsort + basin labeling (descent + pointer jumping)
// + candidate-saddle extraction + tiny wave-0 UF + landscapes.
// One 512-thread block per (m0, b) problem.
//
// Correctness: elder-rule deaths only happen to local-minimum roots;
// same-basin edges are always find-equal no-ops (descent paths connect
// both endpoints below the edge's activation vertex); within-vertex
// union order does not change the dying-root set or death values.
// So UF over basin-differing edges (in reference order) yields pd
// bit-identical to the reference.
// ============================================================
__device__ __forceinline__ int pf_find(volatile float2* pf, int x, unsigned& fbits) {
    float2 e;
    e.x = pf[x].x; e.y = pf[x].y;
    int p = __float_as_int(e.y);
    while (p != x) {
        float2 ep;
        ep.x = pf[p].x; ep.y = pf[p].y;
        int gp = __float_as_int(ep.y);
        if (gp != p) { pf[x].x = ep.x; pf[x].y = ep.y; }   // path halving
        x = p; e = ep; p = gp;
    }
    fbits = __float_as_uint(e.x);
    return x;
}

__global__ __launch_bounds__(512) void topo_kernel(
        const float* __restrict__ fv_g,
        float* __restrict__ feat) {
    __shared__ float skey[NPAD];
    __shared__ short sidx_s[NPAD];
    __shared__ short rank_[N];
    __shared__ int tcnt[NPAD];
    __shared__ int tcnt2[NPAD];
    __shared__ float fv[N];
    __shared__ float2 pf_s[N];
    __shared__ short pd[N];
    __shared__ short labA[N];
    __shared__ short labB[N];
    __shared__ unsigned ev[MEDGE];
    volatile float2* pf = pf_s;

    const int prob = blockIdx.x, tid = threadIdx.x;

    // ---- load f, init sort arrays ----
    for (int j = tid; j < NPAD; j += 512) {
        float v = (j < N) ? fv_g[prob * N + j] : 3.0e38f;
        skey[j] = v;
        sidx_s[j] = (short)j;
        if (j < N) fv[j] = v;
    }
    __syncthreads();
    // ---- stable bitonic argsort ascending by (f, idx) ----
    for (int k = 2; k <= NPAD; k <<= 1) {
        for (int j = k >> 1; j > 0; j >>= 1) {
            for (int a = tid; a < NPAD; a += 512) {
                int b2 = a ^ j;
                if (b2 > a) {
                    float ka = skey[a], kb = skey[b2];
                    short ia = sidx_s[a], ib = sidx_s[b2];
                    bool gt = (ka > kb) || (ka == kb && ia > ib);
                    if (gt == ((a & k) == 0)) {
                        skey[a] = kb; skey[b2] = ka;
                        sidx_s[a] = ib; sidx_s[b2] = ia;
                    }
                }
            }
            __syncthreads();
        }
    }
    // ---- rank, pf, pd init ----
    for (int j = tid; j < N; j += 512) {
        rank_[sidx_s[j]] = (short)j;
        pf_s[j] = make_float2(fv[j], __int_as_float(j));
        pd[j] = (short)j;
    }
    __syncthreads();
    // ---- descent pointers: D[v] = min-rank neighbor if lower ----
    #pragma unroll
    for (int h = 0; h < 2; ++h) {
        int v = tid + h * 512;
        if (v < N) {
            int row = v / H, col = v % H;
            int rv = (int)rank_[v];
            int best = rv, bestn = v;
            if (row > 0)     { int n = v - H, rn = (int)rank_[n]; if (rn < best) { best = rn; bestn = n; } }
            if (row < H - 1) { int n = v + H, rn = (int)rank_[n]; if (rn < best) { best = rn; bestn = n; } }
            if (col > 0)     { int n = v - 1, rn = (int)rank_[n]; if (rn < best) { best = rn; bestn = n; } }
            if (col < H - 1) { int n = v + 1, rn = (int)rank_[n]; if (rn < best) { best = rn; bestn = n; } }
            labA[v] = (short)bestn;
        }
    }
    __syncthreads();
    // ---- pointer jumping to basin minima (2^10 >= any path) ----
    short* lsrc = labA;
    short* ldst = labB;
    for (int it = 0; it < 10; ++it) {
        #pragma unroll
        for (int h = 0; h < 2; ++h) {
            int v = tid + h * 512;
            if (v < N) ldst[v] = lsrc[(int)lsrc[v]];
        }
        __syncthreads();
        short* t = lsrc; lsrc = ldst; ldst = t;
    }
    const short* lab = lsrc;
    // ---- candidate saddle edges: basin(v) != basin(nb), ref order ----
    #pragma unroll
    for (int h = 0; h < 2; ++h) {
        int r = tid + h * 512;
        int deg = 0;
        if (r < N) {
            int v = sidx_s[r];
            int row = v / H, col = v % H;
            int lv = (int)lab[v];
            deg += (row > 0     && (int)rank_[v - H] < r && (int)lab[v - H] != lv);
            deg += (row < H - 1 && (int)rank_[v + H] < r && (int)lab[v + H] != lv);
            deg += (col > 0     && (int)rank_[v - 1] < r && (int)lab[v - 1] != lv);
            deg += (col < H - 1 && (int)rank_[v + 1] < r && (int)lab[v + 1] != lv);
        }
        tcnt[r] = deg;
    }
    __syncthreads();
    // ---- inclusive Hillis-Steele scan over 1024 (ping-pong) ----
    int src_is_a = 1;
    for (int off = 1; off < NPAD; off <<= 1) {
        int* src = src_is_a ? tcnt : tcnt2;
        int* dst = src_is_a ? tcnt2 : tcnt;
        #pragma unroll
        for (int h = 0; h < 2; ++h) {
            int i = tid + h * 512;
            int v = src[i];
            if (i >= off) v += src[i - off];
            dst[i] = v;
        }
        __syncthreads();
        src_is_a ^= 1;
    }
    int* scan = src_is_a ? tcnt : tcnt2;
    // ---- scatter candidate events: u | basin_u<<10 | basin_w<<20 ----
    #pragma unroll
    for (int h = 0; h < 2; ++h) {
        int r = tid + h * 512;
        if (r < N) {
            int v = sidx_s[r];
            int row = v / H, col = v % H;
            int lv = (int)lab[v];
            int nbs[4] = { v - H, v + H, v - 1, v + 1 };
            bool val[4] = { row > 0, row < H - 1, col > 0, col < H - 1 };
            bool cand[4];
            int deg = 0;
            #pragma unroll
            for (int k4 = 0; k4 < 4; ++k4) {
                cand[k4] = val[k4] && (int)rank_[nbs[k4]] < r && (int)lab[nbs[k4]] != lv;
                deg += cand[k4];
            }
            int pos = scan[r] - deg;
            #pragma unroll
            for (int k4 = 0; k4 < 4; ++k4) {
                if (cand[k4]) {
                    ev[pos] = (unsigned)v | ((unsigned)lv << 10)
                            | ((unsigned)(int)lab[nbs[k4]] << 20);
                    pos++;
                }
            }
        }
    }
    __syncthreads();
    const int mc = scan[NPAD - 1];

    // ---- wave-0 tiny UF over candidates (ballot resolve) ----
    if (tid < 64) {
        const int lane = tid;
        const int nch = (mc + 63) >> 6;
        for (int c = 0; c < nch; ++c) {
            int idx = c * 64 + lane;
            unsigned e = (idx < mc) ? ev[idx] : 0u;
            const int uu = (int)(e & 1023u);
            const int bu = (int)((e >> 10) & 1023u);
            const int bw = (int)((e >> 20) & 1023u);
            unsigned fa, fb;
            int ra = pf_find(pf, bu, fa);
            int rb = pf_find(pf, bw, fb);
            int myL = -1, myW = 0; unsigned myWF = 0;
            unsigned long long mask = __ballot(ra != rb);
            while (mask) {
                int j = __builtin_ctzll(mask);
                mask &= mask - 1;
                int s_a = __builtin_amdgcn_readlane(ra, j);
                int s_b = __builtin_amdgcn_readlane(rb, j);
                if (s_a != s_b) {          // uniform
                    unsigned s_fa = (unsigned)__builtin_amdgcn_readlane((int)fa, j);
                    unsigned s_fb = (unsigned)__builtin_amdgcn_readlane((int)fb, j);
                    bool nw = (s_fb < s_fa) || (s_fb == s_fa && s_b < s_a);
                    int s_w = nw ? s_b : s_a;
                    int s_l = nw ? s_a : s_b;
                    unsigned s_wf = nw ? s_fb : s_fa;
                    bool me = (lane == j);
                    myL  = me ? s_l  : myL;
                    myW  = me ? s_w  : myW;
                    myWF = me ? s_wf : myWF;
                    bool ha = (ra == s_l);
                    ra = ha ? s_w : ra; fa = ha ? s_wf : fa;
                    bool hb = (rb == s_l);
                    rb = hb ? s_w : rb; fb = hb ? s_wf : fb;
                }
            }
            // one parallel write round; losers distinct -> race-free
            if (myL >= 0) {
                pd[myL] = (short)uu;
                pf[myL].x = __uint_as_float(myWF);
                pf[myL].y = __int_as_float(myW);
            }
            __builtin_amdgcn_sched_barrier(0);   // writes before next finds
        }
        if (lane == 0) {
            unsigned dummy;
            int vmax = (int)sidx_s[N - 1];
            int g = pf_find(pf, (int)lab[vmax], dummy);
            pd[g] = (short)vmax;
        }
    }
    __syncthreads();

    // ---- landscapes: top-2 of tent functions per t (8 waves) ----
    const int wave = tid >> 6, lane = tid & 63;
    for (int t = wave; t < T; t += 8) {
        float tval = (t == T - 1) ? 80.0f : (1.0f + (float)t * (79.0f / 24.0f));
        float m1 = 0.f, m2 = 0.f;
        for (int i = lane; i < N; i += 64) {
            float bi = fv[i];
            float di = fv[(int)pd[i]];
            float tv = fminf(tval - bi, di - tval);
            tv = fmaxf(tv, 0.f);
            float lo = fminf(tv, m1);
            m1 = fmaxf(tv, m1);
            m2 = fmaxf(m2, lo);
        }
        #pragma unroll
        for (int off = 32; off > 0; off >>= 1) {
            float o1 = __shfl_down(m1, off, 64);
            float o2 = __shfl_down(m2, off, 64);
            float hi = fmaxf(m1, o1);
            float lo = fminf(m1, o1);
            m2 = fmaxf(fmaxf(m2, o2), lo);
            m1 = hi;
        }
        if (lane == 0) {
            feat[prob * 50 + t]     = m1;
            feat[prob * 50 + T + t] = m2;
        }
    }
}

// ============================================================
// K4: head.
// ============================================================
__global__ void head_kernel(const float* __restrict__ feat,
                            const float* __restrict__ wg1, const float* __restrict__ bg1,
                            const float* __restrict__ wg2, const float* __restrict__ bg2,
                            const float* __restrict__ fcw, const float* __restrict__ fcb,
                            float* __restrict__ out) {
    __shared__ float xc[B * 100];
    const int tid = threadIdx.x;
    for (int e = tid; e < B * 100; e += 256) {
        int b = e / 100, j = e % 100;
        const float* fp; const float* wrow; float bias;
        if (j < 50) { fp = feat + b * 50;       wrow = wg1 + j * 50;        bias = bg1[j]; }
        else        { fp = feat + (B + b) * 50; wrow = wg2 + (j - 50) * 50; bias = bg2[j - 50]; }
        float acc = bias;
        for (int q = 0; q < 50; ++q) acc += fp[q] * wrow[q];
        xc[e] = acc;
    }
    __syncthreads();
    for (int j = tid; j < 100; j += 256) {
        float s = 0.f;
        for (int b = 0; b < B; ++b) s += fabsf(xc[b * 100 + j]);
        out[320 + j] = s;
    }
    for (int e = tid; e < 320; e += 256) {
        int b = e / 10, o = e % 10;
        float acc = fcb[o];
        for (int j = 0; j < 100; ++j)
            acc += fmaxf(xc[b * 100 + j], 0.f) * fcw[o * 100 + j];
        out[e] = acc;
    }
}

extern "C" void kernel_launch(void* const* d_in, const int* in_sizes, int n_in,
                              void* d_out, int out_size, void* d_ws, size_t ws_size,
                              hipStream_t stream) {
    (void)in_sizes; (void)n_in; (void)out_size; (void)ws_size;
    const float* x   = (const float*)d_in[0];
    const float* wg1 = (const float*)d_in[1];
    const float* bg1 = (const float*)d_in[2];
    const float* wg2 = (const float*)d_in[3];
    const float* bg2 = (const float*)d_in[4];
    const float* fcw = (const float*)d_in[5];
    const float* fcb = (const float*)d_in[6];
    float* out = (float*)d_out;

    char* ws = (char*)d_ws;
    float*          d2s   = (float*)ws;                                  // N*N f32
    unsigned short* sidxt = (unsigned short*)(ws + (size_t)N * N * 4);   // N*N u16
    float*          fv_g  = (float*)(ws + (size_t)N * N * 6);            // 64*784 f32
    float*          feat  = (float*)(ws + (size_t)N * N * 6 + 64 * N * 4); // 64*50 f32

    sort_d2_kernel<<<dim3(N), dim3(256), 0, stream>>>(d2s, sidxt);
    dtm_kernel<<<dim3(64), dim3(1024), 0, stream>>>(x, d2s, sidxt, fv_g);
    topo_kernel<<<dim3(64), dim3(512), 0, stream>>>(fv_g, feat);
    head_kernel<<<dim3(1), dim3(256), 0, stream>>>(feat, wg1, bg1, wg2, bg2, fcw, fcb, out);
}